// Round 12
// baseline (166.686 us; speedup 1.0000x reference)
//
#include <hip/hip_runtime.h>
#include <hip/hip_bf16.h>

#define DD 128    // feature dim
#define HH 16     // hidden dim
#define BW 128    // bucket width (nodes per bucket) = 1<<7
#define NBMAX 1024
#define SCAP 4096      // LDS slice cap in sortagg
#define XG 384         // xform blocks in k_front

// bf16x2 pack/unpack (RNE)
__device__ __forceinline__ float lo16(unsigned u) { return __uint_as_float(u << 16); }
__device__ __forceinline__ float hi16(unsigned u) { return __uint_as_float(u & 0xffff0000u); }
__device__ __forceinline__ unsigned b16(float f) {
    unsigned u = __float_as_uint(f);
    return (u + 0x7fffu + ((u >> 16) & 1u)) >> 16;
}
__device__ __forceinline__ unsigned pack2(float a, float b) {
    return b16(a) | (b16(b) << 16);
}

typedef __attribute__((ext_vector_type(8))) short bf16x8;   // MFMA A/B frag (4 VGPRs)
typedef __attribute__((ext_vector_type(4))) float f32x4;    // MFMA C/D frag

// ---------------------------------------------------------------------------
// K1 (k_front): fused front (R10/164us structure, unchanged). Three roles:
//   [0, cblocks)  : LOCAL-SORT scatter -> packed[bid*4096..] (coalesced) +
//                   runofs[bid*1024 + b] offsets. No global atomics.
//   cblocks       : classifier-collapse prep (wsu[0..65]).
//   (cblocks,+XG] : xform y1 = x@w1_l (bf16), z1 = x@w1_r (f32) via MFMA.
// ---------------------------------------------------------------------------
__global__ __launch_bounds__(256)
__attribute__((amdgpu_waves_per_eu(1, 4)))
void k_front(const int* __restrict__ src,
             const int* __restrict__ dst,
             int* __restrict__ packed,
             int* __restrict__ runofs,
             int E4, int NB, int cblocks,
             const float* __restrict__ w2l,
             const float* __restrict__ w2r,
             const float* __restrict__ b2v,
             const float* __restrict__ wc,
             const float* __restrict__ bc,
             float* __restrict__ wsu,
             const float* __restrict__ x,
             const float* __restrict__ w1l,
             const float* __restrict__ w1r,
             unsigned* __restrict__ y1b,
             float* __restrict__ z1, int N) {
    __shared__ int hist[NBMAX];
    __shared__ int lofs[NBMAX];    // exclusive offsets; mutated as cursors
    __shared__ int sbuf[4096];
    __shared__ int wss[4];
    const int tid = threadIdx.x;
    const int bid = (int)blockIdx.x;

    if (bid == cblocks) {      // ---- prep block ----
        if (tid < 64) {
            int k = tid >> 4, j = tid & 15;
            const float* W = (k < 2) ? w2l : w2r;
            int off = (k & 1) * DD;
            float s = 0.f;
            for (int d = 0; d < DD; ++d) s += W[j * DD + d] * wc[off + d];
            wsu[k * 16 + j] = s;
        } else if (tid == 64) {
            float s = bc[0];
            for (int d = 0; d < DD; ++d) s += b2v[d] * wc[d];
            wsu[64] = s;
        } else if (tid == 65) {
            float s = 0.f;
            for (int d = 0; d < DD; ++d) s += b2v[d] * wc[DD + d];
            wsu[65] = s;
        }
        return;
    }

    if (bid > cblocks) {       // ---- xform blocks (single-buffered, reg-light) ----
        const int xb   = bid - cblocks - 1;          // 0..XG-1
        const int lane = tid & 63;
        const int m    = lane & 15;
        const int quad = lane >> 4;
        const int nw   = XG * 4;                     // total xform waves
        const int wid  = xb * 4 + (tid >> 6);
        const int ntiles = N >> 4;

        bf16x8 AL[4], AR[4];
#pragma unroll
        for (int kk = 0; kk < 4; ++kk) {
            union { unsigned u[4]; bf16x8 v; } al, ar;
#pragma unroll
            for (int p = 0; p < 4; ++p) {
                int d0 = kk * 32 + quad * 8 + 2 * p;
                al.u[p] = pack2(w1l[(size_t)d0 * HH + m], w1l[(size_t)(d0 + 1) * HH + m]);
                ar.u[p] = pack2(w1r[(size_t)d0 * HH + m], w1r[(size_t)(d0 + 1) * HH + m]);
            }
            AL[kk] = al.v; AR[kk] = ar.v;
        }

        const float4* xg4 = (const float4*)x;
        for (int tile = wid; tile < ntiles; tile += nw) {
            f32x4 accL = {0.f, 0.f, 0.f, 0.f};
            f32x4 accR = {0.f, 0.f, 0.f, 0.f};
#pragma unroll
            for (int kk = 0; kk < 4; ++kk) {
                size_t o = (size_t)(tile * 16 + m) * 32 + kk * 8 + quad * 2;
                float4 a = xg4[o], b = xg4[o + 1];
                union { unsigned u[4]; bf16x8 v; } bx;
                bx.u[0] = pack2(a.x, a.y);
                bx.u[1] = pack2(a.z, a.w);
                bx.u[2] = pack2(b.x, b.y);
                bx.u[3] = pack2(b.z, b.w);
                accL = __builtin_amdgcn_mfma_f32_16x16x32_bf16(AL[kk], bx.v, accL, 0, 0, 0);
                accR = __builtin_amdgcn_mfma_f32_16x16x32_bf16(AR[kk], bx.v, accR, 0, 0, 0);
            }
            int row = tile * 16 + m;
            uint2 yp; yp.x = pack2(accL[0], accL[1]); yp.y = pack2(accL[2], accL[3]);
            ((uint2*)y1b)[(size_t)row * 4 + quad] = yp;
            float4 zf = {accR[0], accR[1], accR[2], accR[3]};
            ((float4*)z1)[(size_t)row * 4 + quad] = zf;
        }

        // scalar tail for N % 16 (not hit when N % 16 == 0)
        const int tail0 = ntiles << 4;
        if (tail0 < N && xb == 0) {
            for (int idx = tid; idx < (N - tail0) * HH; idx += 256) {
                int row = tail0 + (idx >> 4), n = idx & 15;
                float sl = 0.f, sr = 0.f;
                for (int d = 0; d < DD; ++d) {
                    float xv = x[(size_t)row * DD + d];
                    sl += xv * w1l[(size_t)d * HH + n];
                    sr += xv * w1r[(size_t)d * HH + n];
                }
                ((unsigned short*)y1b)[(size_t)row * 16 + n] = (unsigned short)b16(sl);
                z1[(size_t)row * HH + n] = sr;
            }
        }
        return;
    }

    // ---- scat blocks: local counting sort + coalesced write ----
    for (int i = tid; i < NBMAX; i += 256) hist[i] = 0;   // zero-pad for scan
    __syncthreads();
    int base = bid * 1024;                                // int4 units
    int4 dreg[4];
#pragma unroll
    for (int k = 0; k < 4; ++k) {
        int i4 = base + k * 256 + tid;
        if (i4 < E4) {
            int4 d = ((const int4*)dst)[i4];
            dreg[k] = d;
            atomicAdd(&hist[d.x >> 7], 1);
            atomicAdd(&hist[d.y >> 7], 1);
            atomicAdd(&hist[d.z >> 7], 1);
            atomicAdd(&hist[d.w >> 7], 1);
        }
    }
    __syncthreads();
    // exclusive scan of 1024 entries (4/thread + wave scan + combine)
    {
        int cb = tid * 4;
        int a0 = hist[cb], a1 = hist[cb + 1], a2 = hist[cb + 2], a3 = hist[cb + 3];
        int s1 = a0 + a1, s2 = s1 + a2, tot = s2 + a3;
        int lane = tid & 63;
        int inc = tot;
#pragma unroll
        for (int off = 1; off < 64; off <<= 1) {
            int u = __shfl_up(inc, off, 64);
            if (lane >= off) inc += u;
        }
        if (lane == 63) wss[tid >> 6] = inc;
        __syncthreads();
        int w = tid >> 6, woff = 0;
#pragma unroll
        for (int k2 = 0; k2 < 4; ++k2) if (k2 < w) woff += wss[k2];
        int e0 = woff + inc - tot;
        lofs[cb]     = e0;
        lofs[cb + 1] = e0 + a0;
        lofs[cb + 2] = e0 + s1;
        lofs[cb + 3] = e0 + s2;
    }
    __syncthreads();
    // publish per-(block,bucket) offsets BEFORE cursors mutate (coalesced)
    for (int b2 = tid; b2 <= NB; b2 += 256)
        runofs[(size_t)bid * 1024 + b2] = lofs[b2];
    __syncthreads();
    // counting-sort into sbuf (lofs doubles as cursor array)
#pragma unroll
    for (int k = 0; k < 4; ++k) {
        int i4 = base + k * 256 + tid;
        if (i4 < E4) {
            int4 sv = ((const int4*)src)[i4];
            int4 d = dreg[k];
            int p;
            p = atomicAdd(&lofs[d.x >> 7], 1); sbuf[p] = ((d.x & 127) << 20) | sv.x;
            p = atomicAdd(&lofs[d.y >> 7], 1); sbuf[p] = ((d.y & 127) << 20) | sv.y;
            p = atomicAdd(&lofs[d.z >> 7], 1); sbuf[p] = ((d.z & 127) << 20) | sv.z;
            p = atomicAdd(&lofs[d.w >> 7], 1); sbuf[p] = ((d.w & 127) << 20) | sv.w;
        }
    }
    __syncthreads();
    // coalesced stream write of the sorted block
    int rem = (E4 - base) * 4;
    int ec = rem < 4096 ? rem : 4096;
    for (int i = tid; i < ec; i += 256)
        packed[(size_t)bid * 4096 + i] = sbuf[i];
}

// ---------------------------------------------------------------------------
// K5: one block per bucket. Phase A (R11-verified): gather the bucket's
// cblocks runs into LDS (2 runs/thread + wave scan), counting sort -> sbuf,
// write nodestart/ncnt/csr (gapped at b<<12).
// Phase B (NEW: 2 lanes/node, uint4): lane sg in {0,1} reads the 16B half
// of each neighbor's 32B y1 row -> half the gather instructions of the
// 4-lane-uint2 form, one pass over all 128 nodes. h = relu(mean + b1 + z1),
// classifier collapse with half-dots, one shfl_xor(1,2) merge, lanes 0/1
// write q/p planes.
// ---------------------------------------------------------------------------
__global__ __launch_bounds__(256) void k_sortagg(const int* __restrict__ packed,
                                                 const int* __restrict__ runofs,
                                                 int cblocks,
                                                 int* __restrict__ nodestart,
                                                 int* __restrict__ ncnt,
                                                 int* __restrict__ csr,
                                                 const unsigned* __restrict__ y1b,
                                                 const float* __restrict__ z1,
                                                 const float* __restrict__ b1,
                                                 const float* __restrict__ wsu,
                                                 float* __restrict__ qarr,
                                                 float* __restrict__ parr,
                                                 int N) {
    __shared__ int buf[SCAP];
    __shared__ int sbuf[SCAP];
    __shared__ int hist[BW];
    __shared__ int exs[BW];
    __shared__ int curs[BW];
    __shared__ int wss[4];
    __shared__ int wtot;
    const int tid = threadIdx.x;
    const int b = blockIdx.x;
    const int st = b << 12;                 // gapped csr base

    if (tid < BW) hist[tid] = 0;

    // ---- run descriptors: 2 runs per thread ----
    const int r0 = tid * 2, r1 = r0 + 1;
    int s0g = 0, c0 = 0, s1g = 0, c1 = 0;
    if (r0 < cblocks) {
        s0g = runofs[(size_t)r0 * 1024 + b];
        c0  = runofs[(size_t)r0 * 1024 + b + 1] - s0g;
    }
    if (r1 < cblocks) {
        s1g = runofs[(size_t)r1 * 1024 + b];
        c1  = runofs[(size_t)r1 * 1024 + b + 1] - s1g;
    }
    int pr = c0 + c1;
    int lane = tid & 63;
    int inc = pr;
#pragma unroll
    for (int off = 1; off < 64; off <<= 1) {
        int u = __shfl_up(inc, off, 64);
        if (lane >= off) inc += u;
    }
    if (lane == 63) wss[tid >> 6] = inc;
    __syncthreads();                         // also covers hist zeroing
    int w = tid >> 6, woff = 0;
#pragma unroll
    for (int k2 = 0; k2 < 4; ++k2) if (k2 < w) woff += wss[k2];
    int excl = woff + inc - pr;              // buf position for run r0
    int cnt = wss[0] + wss[1] + wss[2] + wss[3];
    if (cnt > SCAP) cnt = SCAP;              // never hit (max ~2300); defensive

    // ---- gather this thread's two runs into buf (+ node hist) ----
    for (int j = 0; j < c0; ++j) {
        int e = packed[(size_t)r0 * 4096 + s0g + j];
        buf[excl + j] = e;
        atomicAdd(&hist[e >> 20], 1);
    }
    int exb = excl + c0;
    for (int j = 0; j < c1; ++j) {
        int e = packed[(size_t)r1 * 4096 + s1g + j];
        buf[exb + j] = e;
        atomicAdd(&hist[e >> 20], 1);
    }
    __syncthreads();

    // ---- node-level exclusive scan (128 entries) ----
    int v = 0, s = 0;
    if (tid < BW) {
        v = hist[tid];
        s = v;
#pragma unroll
        for (int off = 1; off < 64; off <<= 1) {
            int u = __shfl_up(s, off, 64);
            if (lane >= off) s += u;
        }
        if (tid == 63) wtot = s;
    }
    __syncthreads();
    if (tid < BW) {
        int ex = s - v + ((tid >= 64) ? wtot : 0);
        exs[tid] = ex;
        curs[tid] = ex;
        int node = (b << 7) + tid;
        if (node < N) { nodestart[node] = st + ex; ncnt[node] = v; }
    }
    __syncthreads();

    for (int i = tid; i < cnt; i += 256) {
        int e = buf[i];
        int p = atomicAdd(&curs[e >> 20], 1);
        sbuf[p] = e & 0xFFFFF;
    }
    __syncthreads();
    for (int i = tid; i < cnt; i += 256) csr[st + i] = sbuf[i];  // coalesced

    // ---- Phase B: 2 lanes/node, uint4 half-row gathers, single pass ----
    const uint4* f4 = (const uint4*)y1b;
    const int l = tid >> 1;          // node slot 0..127
    const int sg = tid & 1;          // 16B half of the 32B y1 row
    const float4* wsu4 = (const float4*)wsu;
    const float4 U0a = wsu4[sg * 2],      U0b = wsu4[sg * 2 + 1];       // u_0 half
    const float4 U1a = wsu4[4 + sg * 2],  U1b = wsu4[4 + sg * 2 + 1];   // u_1 half
    const float4 U2a = wsu4[8 + sg * 2],  U2b = wsu4[8 + sg * 2 + 1];   // r_0 half
    const float4 U3a = wsu4[12 + sg * 2], U3b = wsu4[12 + sg * 2 + 1];  // r_1 half
    int node = (b << 7) + l;
    if (node < N) {
        int s0 = exs[l], c = hist[l];
        float a0 = 0.f, a1 = 0.f, a2 = 0.f, a3 = 0.f;
        float a4 = 0.f, a5 = 0.f, a6 = 0.f, a7 = 0.f;
        int k = 0;
        for (; k + 4 <= c; k += 4) {
            uint4 ya = f4[(size_t)(sbuf[s0 + k]     * 2 + sg)];
            uint4 yb = f4[(size_t)(sbuf[s0 + k + 1] * 2 + sg)];
            uint4 yc = f4[(size_t)(sbuf[s0 + k + 2] * 2 + sg)];
            uint4 yd = f4[(size_t)(sbuf[s0 + k + 3] * 2 + sg)];
            a0 += (lo16(ya.x) + lo16(yb.x)) + (lo16(yc.x) + lo16(yd.x));
            a1 += (hi16(ya.x) + hi16(yb.x)) + (hi16(yc.x) + hi16(yd.x));
            a2 += (lo16(ya.y) + lo16(yb.y)) + (lo16(yc.y) + lo16(yd.y));
            a3 += (hi16(ya.y) + hi16(yb.y)) + (hi16(yc.y) + hi16(yd.y));
            a4 += (lo16(ya.z) + lo16(yb.z)) + (lo16(yc.z) + lo16(yd.z));
            a5 += (hi16(ya.z) + hi16(yb.z)) + (hi16(yc.z) + hi16(yd.z));
            a6 += (lo16(ya.w) + lo16(yb.w)) + (lo16(yc.w) + lo16(yd.w));
            a7 += (hi16(ya.w) + hi16(yb.w)) + (hi16(yc.w) + hi16(yd.w));
        }
        for (; k < c; ++k) {
            uint4 ya = f4[(size_t)(sbuf[s0 + k] * 2 + sg)];
            a0 += lo16(ya.x); a1 += hi16(ya.x);
            a2 += lo16(ya.y); a3 += hi16(ya.y);
            a4 += lo16(ya.z); a5 += hi16(ya.z);
            a6 += lo16(ya.w); a7 += hi16(ya.w);
        }
        float inv = 1.f / fmaxf((float)c, 1.f);
        const float4* z4 = (const float4*)z1;   // 16 f32/row
        float4 zA = z4[(size_t)node * 4 + sg * 2];
        float4 zB = z4[(size_t)node * 4 + sg * 2 + 1];
        const float4* b4 = (const float4*)b1;
        float4 bA = b4[sg * 2], bB = b4[sg * 2 + 1];
        float h0 = fmaxf(a0 * inv + bA.x + zA.x, 0.f);
        float h1 = fmaxf(a1 * inv + bA.y + zA.y, 0.f);
        float h2 = fmaxf(a2 * inv + bA.z + zA.z, 0.f);
        float h3 = fmaxf(a3 * inv + bA.w + zA.w, 0.f);
        float h4 = fmaxf(a4 * inv + bB.x + zB.x, 0.f);
        float h5 = fmaxf(a5 * inv + bB.y + zB.y, 0.f);
        float h6 = fmaxf(a6 * inv + bB.z + zB.z, 0.f);
        float h7 = fmaxf(a7 * inv + bB.w + zB.w, 0.f);
        float d0 = h0 * U0a.x + h1 * U0a.y + h2 * U0a.z + h3 * U0a.w
                 + h4 * U0b.x + h5 * U0b.y + h6 * U0b.z + h7 * U0b.w;
        float d1 = h0 * U1a.x + h1 * U1a.y + h2 * U1a.z + h3 * U1a.w
                 + h4 * U1b.x + h5 * U1b.y + h6 * U1b.z + h7 * U1b.w;
        float d2 = h0 * U2a.x + h1 * U2a.y + h2 * U2a.z + h3 * U2a.w
                 + h4 * U2b.x + h5 * U2b.y + h6 * U2b.z + h7 * U2b.w;
        float d3 = h0 * U3a.x + h1 * U3a.y + h2 * U3a.z + h3 * U3a.w
                 + h4 * U3b.x + h5 * U3b.y + h6 * U3b.z + h7 * U3b.w;
        // merge sg halves (lanes tid even <-> odd)
        d0 += __shfl_xor(d0, 1, 2);
        d1 += __shfl_xor(d1, 1, 2);
        d2 += __shfl_xor(d2, 1, 2);
        d3 += __shfl_xor(d3, 1, 2);
        if (sg == 0) { qarr[node] = d0; parr[node] = d2; }
        else         { qarr[(size_t)N + node] = d1; parr[(size_t)N + node] = d3; }
    }
}

// ---------------------------------------------------------------------------
// K6: pair logits + BCE from collapsed scalars. 8 lanes/pair (R6-verified
// form): 512 blocks = 2 blocks/CU. s = sub>>2 (article slot), part = sub&3
// (edge 4-way split) -> per-lane serial csr->q chain is ~c/4 long.
// ---------------------------------------------------------------------------
__global__ __launch_bounds__(256) void k_pair(const float* __restrict__ qarr,
                                              const float* __restrict__ parr,
                                              const int* __restrict__ csr,
                                              const int* __restrict__ nodestart,
                                              const int* __restrict__ ncnt,
                                              const int* __restrict__ a1,
                                              const int* __restrict__ a2,
                                              const int* __restrict__ labels,
                                              const float* __restrict__ wsu,
                                              float* __restrict__ out_logits,
                                              float* __restrict__ lacc,
                                              int* __restrict__ ticket,
                                              float* __restrict__ out0,
                                              int B, float invB, int N) {
    __shared__ float lred[4];
    int t = blockIdx.x * 256 + threadIdx.x;
    int pid = t >> 3, sub = t & 7;
    int s = sub >> 2, part = sub & 3;

    float hsum = 0.f;
    if (pid < B) {
        int node = s ? a2[pid] : a1[pid];
        int st = nodestart[node];
        int c = ncnt[node];
        const float* qs = qarr + (size_t)s * N;
        const int* ids = csr + st;
        float acc = 0.f;
        int k = part;
        for (; k + 4 < c; k += 8) {              // this lane: edges k, k+4
            int n0 = ids[k], n1 = ids[k + 4];
            acc += qs[n0] + qs[n1];
        }
        if (k < c) acc += qs[ids[k]];
        acc += __shfl_xor(acc, 1, 4);
        acc += __shfl_xor(acc, 2, 4);
        hsum = acc / fmaxf((float)c, 1.f) + parr[(size_t)s * N + node];
    }
    float other = __shfl_xor(hsum, 4, 8);
    float myloss = 0.f;
    if (pid < B && sub == 0) {
        float l = hsum + other + wsu[64] + wsu[65];
        out_logits[pid] = l;
        float y = (float)labels[pid];
        myloss = fmaxf(l, 0.f) - l * y + log1pf(expf(-fabsf(l)));
    }
    // block loss reduction
    float v = myloss;
#pragma unroll
    for (int off = 32; off; off >>= 1) v += __shfl_down(v, off, 64);
    if ((threadIdx.x & 63) == 0) lred[threadIdx.x >> 6] = v;
    __syncthreads();
    if (threadIdx.x == 0) {
        float ssum = lred[0] + lred[1] + lred[2] + lred[3];
        atomicAdd(lacc, ssum);
        __threadfence();
        int tk = atomicAdd(ticket, 1);
        if (tk == (int)gridDim.x - 1) {
            __threadfence();
            float total = atomicAdd(lacc, 0.f);
            out0[0] = total * invB;
        }
    }
}

// ---------------------------------------------------------------------------
extern "C" void kernel_launch(void* const* d_in, const int* in_sizes, int n_in,
                              void* d_out, int out_size, void* d_ws, size_t ws_size,
                              hipStream_t stream) {
    const float* x    = (const float*)d_in[0];
    const float* w1l  = (const float*)d_in[1];
    const float* b1   = (const float*)d_in[2];
    const float* w1r  = (const float*)d_in[3];
    const float* w2l  = (const float*)d_in[4];
    const float* b2v  = (const float*)d_in[5];
    const float* w2r  = (const float*)d_in[6];
    const float* wc   = (const float*)d_in[7];
    const float* bc   = (const float*)d_in[8];
    const int*   ei   = (const int*)d_in[9];
    const int*   a1   = (const int*)d_in[10];
    const int*   a2   = (const int*)d_in[11];
    const int*   lab  = (const int*)d_in[12];

    const int N = in_sizes[0] / DD;
    const int E = in_sizes[9] / 2;
    const int B = in_sizes[10];
    const int NB = (N + BW - 1) / BW;       // 782 for N=100000 (needs N < 2^20)

    const int* src = ei;
    const int* dst = ei + E;

    const int E4 = E / 4;
    const int cblocks = (E4 + 1023) / 1024;          // 4096 edges per chunk

    // workspace layout
    char* ws = (char*)d_ws;
    float*    wsu    = (float*)ws;                            // 512 B
    unsigned* y1b    = (unsigned*)(ws + 512);                 // [N,16] bf16 (32 B/row)
    float*    z1     = (float*)   (ws + 512 + (size_t)N * 32);// [N,16] f32
    int*      packed = (int*)     (ws + 512 + (size_t)N * 96);// [cblocks*4096] sorted blocks
    const size_t PKSZ = (size_t)cblocks * 4096 * 4;
    int*      runofs = (int*)((char*)packed + PKSZ);          // [cblocks*1024] offsets
    const size_t RSZ  = (size_t)cblocks * 1024 * 4;
    int*      csr    = (int*)((char*)runofs + RSZ);           // [NB*4096] gapped
    const size_t CSZ  = (size_t)NB * 4096 * 4;
    char*     p4     = (char*)csr + CSZ;
    int*   nodest  = (int*)p4;                               // [N]
    int*   ncnt    = (int*)(p4 + (size_t)N * 4);             // [N]
    float* qarr    = (float*)(p4 + (size_t)N * 8);           // [2N] planes q0,q1
    float* parr    = (float*)(p4 + (size_t)N * 16);          // [2N] planes p0,p1
    float* lacc    = (float*)(p4 + (size_t)N * 24);          // zeroed
    int*   ticket  = (int*)((char*)lacc + 4);                // zeroed

    float* out = (float*)d_out;       // out[0] = loss, out[1..B] = logits

    hipMemsetAsync((void*)lacc, 0, 8, stream);

    k_front<<<cblocks + 1 + XG, 256, 0, stream>>>(src, dst, packed, runofs,
                                                  E4, NB, cblocks,
                                                  w2l, w2r, b2v, wc, bc, wsu,
                                                  x, w1l, w1r, y1b, z1, N);

    k_sortagg<<<NB, 256, 0, stream>>>(packed, runofs, cblocks,
                                      nodest, ncnt, csr,
                                      y1b, z1, b1, wsu, qarr, parr, N);

    k_pair<<<(B * 8 + 255) / 256, 256, 0, stream>>>(qarr, parr, csr, nodest, ncnt,
                                                    a1, a2, lab, wsu,
                                                    out + 1, lacc, ticket, out,
                                                    B, 1.0f / (float)B, N);
}

// Round 13
// 159.718 us; speedup vs baseline: 1.0436x; 1.0436x over previous
//
#include <hip/hip_runtime.h>
#include <hip/hip_bf16.h>

#define DD 128    // feature dim
#define HH 16     // hidden dim
#define BW 128    // bucket width (nodes per bucket) = 1<<7
#define NBMAX 1024
#define SCAP 4096      // LDS slice cap in sortagg
#define XG 384         // xform blocks in k_front

// bf16x2 pack/unpack (RNE)
__device__ __forceinline__ float lo16(unsigned u) { return __uint_as_float(u << 16); }
__device__ __forceinline__ float hi16(unsigned u) { return __uint_as_float(u & 0xffff0000u); }
__device__ __forceinline__ unsigned b16(float f) {
    unsigned u = __float_as_uint(f);
    return (u + 0x7fffu + ((u >> 16) & 1u)) >> 16;
}
__device__ __forceinline__ unsigned pack2(float a, float b) {
    return b16(a) | (b16(b) << 16);
}

typedef __attribute__((ext_vector_type(8))) short bf16x8;   // MFMA A/B frag (4 VGPRs)
typedef __attribute__((ext_vector_type(4))) float f32x4;    // MFMA C/D frag

// ---------------------------------------------------------------------------
// K1 (k_front): fused front (R10 164us structure, measured best). Roles:
//   [0, cblocks)  : LOCAL-SORT scatter -> packed[bid*4096..] (coalesced) +
//                   runofs[bid*1024 + b] offsets. No global atomics.
//   cblocks       : classifier-collapse prep (wsu[0..65]) + zero lacc/ticket
//                   (replaces the 8-byte hipMemsetAsync launch; front
//                   completes two kernel boundaries before k_pair reads them).
//   (cblocks,+XG] : xform y1 = x@w1_l (bf16), z1 = x@w1_r (f32) via MFMA.
// ---------------------------------------------------------------------------
__global__ __launch_bounds__(256)
__attribute__((amdgpu_waves_per_eu(1, 4)))
void k_front(const int* __restrict__ src,
             const int* __restrict__ dst,
             int* __restrict__ packed,
             int* __restrict__ runofs,
             int E4, int NB, int cblocks,
             const float* __restrict__ w2l,
             const float* __restrict__ w2r,
             const float* __restrict__ b2v,
             const float* __restrict__ wc,
             const float* __restrict__ bc,
             float* __restrict__ wsu,
             const float* __restrict__ x,
             const float* __restrict__ w1l,
             const float* __restrict__ w1r,
             unsigned* __restrict__ y1b,
             float* __restrict__ z1, int N,
             float* __restrict__ lacc,
             int* __restrict__ ticket) {
    __shared__ int hist[NBMAX];
    __shared__ int lofs[NBMAX];    // exclusive offsets; mutated as cursors
    __shared__ int sbuf[4096];
    __shared__ int wss[4];
    const int tid = threadIdx.x;
    const int bid = (int)blockIdx.x;

    if (bid == cblocks) {      // ---- prep block ----
        if (tid < 64) {
            int k = tid >> 4, j = tid & 15;
            const float* W = (k < 2) ? w2l : w2r;
            int off = (k & 1) * DD;
            float s = 0.f;
            for (int d = 0; d < DD; ++d) s += W[j * DD + d] * wc[off + d];
            wsu[k * 16 + j] = s;
        } else if (tid == 64) {
            float s = bc[0];
            for (int d = 0; d < DD; ++d) s += b2v[d] * wc[d];
            wsu[64] = s;
        } else if (tid == 65) {
            float s = 0.f;
            for (int d = 0; d < DD; ++d) s += b2v[d] * wc[DD + d];
            wsu[65] = s;
        } else if (tid == 66) {
            lacc[0] = 0.f;
            ticket[0] = 0;
        }
        return;
    }

    if (bid > cblocks) {       // ---- xform blocks (single-buffered, reg-light) ----
        const int xb   = bid - cblocks - 1;          // 0..XG-1
        const int lane = tid & 63;
        const int m    = lane & 15;
        const int quad = lane >> 4;
        const int nw   = XG * 4;                     // total xform waves
        const int wid  = xb * 4 + (tid >> 6);
        const int ntiles = N >> 4;

        bf16x8 AL[4], AR[4];
#pragma unroll
        for (int kk = 0; kk < 4; ++kk) {
            union { unsigned u[4]; bf16x8 v; } al, ar;
#pragma unroll
            for (int p = 0; p < 4; ++p) {
                int d0 = kk * 32 + quad * 8 + 2 * p;
                al.u[p] = pack2(w1l[(size_t)d0 * HH + m], w1l[(size_t)(d0 + 1) * HH + m]);
                ar.u[p] = pack2(w1r[(size_t)d0 * HH + m], w1r[(size_t)(d0 + 1) * HH + m]);
            }
            AL[kk] = al.v; AR[kk] = ar.v;
        }

        const float4* xg4 = (const float4*)x;
        for (int tile = wid; tile < ntiles; tile += nw) {
            f32x4 accL = {0.f, 0.f, 0.f, 0.f};
            f32x4 accR = {0.f, 0.f, 0.f, 0.f};
#pragma unroll
            for (int kk = 0; kk < 4; ++kk) {
                size_t o = (size_t)(tile * 16 + m) * 32 + kk * 8 + quad * 2;
                float4 a = xg4[o], b = xg4[o + 1];
                union { unsigned u[4]; bf16x8 v; } bx;
                bx.u[0] = pack2(a.x, a.y);
                bx.u[1] = pack2(a.z, a.w);
                bx.u[2] = pack2(b.x, b.y);
                bx.u[3] = pack2(b.z, b.w);
                accL = __builtin_amdgcn_mfma_f32_16x16x32_bf16(AL[kk], bx.v, accL, 0, 0, 0);
                accR = __builtin_amdgcn_mfma_f32_16x16x32_bf16(AR[kk], bx.v, accR, 0, 0, 0);
            }
            int row = tile * 16 + m;
            uint2 yp; yp.x = pack2(accL[0], accL[1]); yp.y = pack2(accL[2], accL[3]);
            ((uint2*)y1b)[(size_t)row * 4 + quad] = yp;
            float4 zf = {accR[0], accR[1], accR[2], accR[3]};
            ((float4*)z1)[(size_t)row * 4 + quad] = zf;
        }

        // scalar tail for N % 16 (not hit when N % 16 == 0)
        const int tail0 = ntiles << 4;
        if (tail0 < N && xb == 0) {
            for (int idx = tid; idx < (N - tail0) * HH; idx += 256) {
                int row = tail0 + (idx >> 4), n = idx & 15;
                float sl = 0.f, sr = 0.f;
                for (int d = 0; d < DD; ++d) {
                    float xv = x[(size_t)row * DD + d];
                    sl += xv * w1l[(size_t)d * HH + n];
                    sr += xv * w1r[(size_t)d * HH + n];
                }
                ((unsigned short*)y1b)[(size_t)row * 16 + n] = (unsigned short)b16(sl);
                z1[(size_t)row * HH + n] = sr;
            }
        }
        return;
    }

    // ---- scat blocks: local counting sort + coalesced write ----
    for (int i = tid; i < NBMAX; i += 256) hist[i] = 0;   // zero-pad for scan
    __syncthreads();
    int base = bid * 1024;                                // int4 units
    int4 dreg[4];
#pragma unroll
    for (int k = 0; k < 4; ++k) {
        int i4 = base + k * 256 + tid;
        if (i4 < E4) {
            int4 d = ((const int4*)dst)[i4];
            dreg[k] = d;
            atomicAdd(&hist[d.x >> 7], 1);
            atomicAdd(&hist[d.y >> 7], 1);
            atomicAdd(&hist[d.z >> 7], 1);
            atomicAdd(&hist[d.w >> 7], 1);
        }
    }
    __syncthreads();
    // exclusive scan of 1024 entries (4/thread + wave scan + combine)
    {
        int cb = tid * 4;
        int a0 = hist[cb], a1 = hist[cb + 1], a2 = hist[cb + 2], a3 = hist[cb + 3];
        int s1 = a0 + a1, s2 = s1 + a2, tot = s2 + a3;
        int lane = tid & 63;
        int inc = tot;
#pragma unroll
        for (int off = 1; off < 64; off <<= 1) {
            int u = __shfl_up(inc, off, 64);
            if (lane >= off) inc += u;
        }
        if (lane == 63) wss[tid >> 6] = inc;
        __syncthreads();
        int w = tid >> 6, woff = 0;
#pragma unroll
        for (int k2 = 0; k2 < 4; ++k2) if (k2 < w) woff += wss[k2];
        int e0 = woff + inc - tot;
        lofs[cb]     = e0;
        lofs[cb + 1] = e0 + a0;
        lofs[cb + 2] = e0 + s1;
        lofs[cb + 3] = e0 + s2;
    }
    __syncthreads();
    // publish per-(block,bucket) offsets BEFORE cursors mutate (coalesced)
    for (int b2 = tid; b2 <= NB; b2 += 256)
        runofs[(size_t)bid * 1024 + b2] = lofs[b2];
    __syncthreads();
    // counting-sort into sbuf (lofs doubles as cursor array)
#pragma unroll
    for (int k = 0; k < 4; ++k) {
        int i4 = base + k * 256 + tid;
        if (i4 < E4) {
            int4 sv = ((const int4*)src)[i4];
            int4 d = dreg[k];
            int p;
            p = atomicAdd(&lofs[d.x >> 7], 1); sbuf[p] = ((d.x & 127) << 20) | sv.x;
            p = atomicAdd(&lofs[d.y >> 7], 1); sbuf[p] = ((d.y & 127) << 20) | sv.y;
            p = atomicAdd(&lofs[d.z >> 7], 1); sbuf[p] = ((d.z & 127) << 20) | sv.z;
            p = atomicAdd(&lofs[d.w >> 7], 1); sbuf[p] = ((d.w & 127) << 20) | sv.w;
        }
    }
    __syncthreads();
    // coalesced stream write of the sorted block
    int rem = (E4 - base) * 4;
    int ec = rem < 4096 ? rem : 4096;
    for (int i = tid; i < ec; i += 256)
        packed[(size_t)bid * 4096 + i] = sbuf[i];
}

// ---------------------------------------------------------------------------
// K5: one block per bucket. Phase A: gather the bucket's cblocks runs into
// LDS (2 runs/thread + wave scan), counting sort -> sbuf, write
// nodestart/ncnt/csr (gapped at b<<12).
// Phase B (R11 measured-best 4-lane uint2 form): layer-1 mean ->
// h = relu(mean + b1 + z1) -> classifier collapse q_s = h.u_s, p_s = h.r_s.
// ---------------------------------------------------------------------------
__global__ __launch_bounds__(256) void k_sortagg(const int* __restrict__ packed,
                                                 const int* __restrict__ runofs,
                                                 int cblocks,
                                                 int* __restrict__ nodestart,
                                                 int* __restrict__ ncnt,
                                                 int* __restrict__ csr,
                                                 const unsigned* __restrict__ y1b,
                                                 const float* __restrict__ z1,
                                                 const float* __restrict__ b1,
                                                 const float* __restrict__ wsu,
                                                 float* __restrict__ qarr,
                                                 float* __restrict__ parr,
                                                 int N) {
    __shared__ int buf[SCAP];
    __shared__ int sbuf[SCAP];
    __shared__ int hist[BW];
    __shared__ int exs[BW];
    __shared__ int curs[BW];
    __shared__ int wss[4];
    __shared__ int wtot;
    const int tid = threadIdx.x;
    const int b = blockIdx.x;
    const int st = b << 12;                 // gapped csr base

    if (tid < BW) hist[tid] = 0;

    // ---- run descriptors: 2 runs per thread ----
    const int r0 = tid * 2, r1 = r0 + 1;
    int s0g = 0, c0 = 0, s1g = 0, c1 = 0;
    if (r0 < cblocks) {
        s0g = runofs[(size_t)r0 * 1024 + b];
        c0  = runofs[(size_t)r0 * 1024 + b + 1] - s0g;
    }
    if (r1 < cblocks) {
        s1g = runofs[(size_t)r1 * 1024 + b];
        c1  = runofs[(size_t)r1 * 1024 + b + 1] - s1g;
    }
    int pr = c0 + c1;
    int lane = tid & 63;
    int inc = pr;
#pragma unroll
    for (int off = 1; off < 64; off <<= 1) {
        int u = __shfl_up(inc, off, 64);
        if (lane >= off) inc += u;
    }
    if (lane == 63) wss[tid >> 6] = inc;
    __syncthreads();                         // also covers hist zeroing
    int w = tid >> 6, woff = 0;
#pragma unroll
    for (int k2 = 0; k2 < 4; ++k2) if (k2 < w) woff += wss[k2];
    int excl = woff + inc - pr;              // buf position for run r0
    int cnt = wss[0] + wss[1] + wss[2] + wss[3];
    if (cnt > SCAP) cnt = SCAP;              // never hit (max ~2300); defensive

    // ---- gather this thread's two runs into buf (+ node hist) ----
    for (int j = 0; j < c0; ++j) {
        int e = packed[(size_t)r0 * 4096 + s0g + j];
        buf[excl + j] = e;
        atomicAdd(&hist[e >> 20], 1);
    }
    int exb = excl + c0;
    for (int j = 0; j < c1; ++j) {
        int e = packed[(size_t)r1 * 4096 + s1g + j];
        buf[exb + j] = e;
        atomicAdd(&hist[e >> 20], 1);
    }
    __syncthreads();

    // ---- node-level exclusive scan (128 entries) ----
    int v = 0, s = 0;
    if (tid < BW) {
        v = hist[tid];
        s = v;
#pragma unroll
        for (int off = 1; off < 64; off <<= 1) {
            int u = __shfl_up(s, off, 64);
            if (lane >= off) s += u;
        }
        if (tid == 63) wtot = s;
    }
    __syncthreads();
    if (tid < BW) {
        int ex = s - v + ((tid >= 64) ? wtot : 0);
        exs[tid] = ex;
        curs[tid] = ex;
        int node = (b << 7) + tid;
        if (node < N) { nodestart[node] = st + ex; ncnt[node] = v; }
    }
    __syncthreads();

    for (int i = tid; i < cnt; i += 256) {
        int e = buf[i];
        int p = atomicAdd(&curs[e >> 20], 1);
        sbuf[p] = e & 0xFFFFF;
    }
    __syncthreads();
    for (int i = tid; i < cnt; i += 256) csr[st + i] = sbuf[i];  // coalesced

    // ---- Phase B: 4 lanes/node, 2 halves (R11 measured-best form) ----
    const uint2* f2 = (const uint2*)y1b;
    const int seg = tid & 3;
    const float4* wsu4 = (const float4*)wsu;
    const float4 U0 = wsu4[seg];        // u_0[seg*4..]
    const float4 U1 = wsu4[4 + seg];    // u_1
    const float4 U2 = wsu4[8 + seg];    // r_0
    const float4 U3 = wsu4[12 + seg];   // r_1
#pragma unroll
    for (int half = 0; half < 2; ++half) {
        int l = (tid >> 2) + half * 64;
        int node = (b << 7) + l;
        if (node < N) {
            int s0 = exs[l], c = hist[l];
            float ax = 0.f, ay = 0.f, az = 0.f, aw = 0.f;
            int k = 0;
            for (; k + 4 <= c; k += 4) {
                uint2 a = f2[(size_t)(sbuf[s0 + k]     * 4 + seg)];
                uint2 bv = f2[(size_t)(sbuf[s0 + k + 1] * 4 + seg)];
                uint2 cv = f2[(size_t)(sbuf[s0 + k + 2] * 4 + seg)];
                uint2 dv = f2[(size_t)(sbuf[s0 + k + 3] * 4 + seg)];
                ax += (lo16(a.x) + lo16(bv.x)) + (lo16(cv.x) + lo16(dv.x));
                ay += (hi16(a.x) + hi16(bv.x)) + (hi16(cv.x) + hi16(dv.x));
                az += (lo16(a.y) + lo16(bv.y)) + (lo16(cv.y) + lo16(dv.y));
                aw += (hi16(a.y) + hi16(bv.y)) + (hi16(cv.y) + hi16(dv.y));
            }
            for (; k < c; ++k) {
                uint2 a = f2[(size_t)(sbuf[s0 + k] * 4 + seg)];
                ax += lo16(a.x); ay += hi16(a.x);
                az += lo16(a.y); aw += hi16(a.y);
            }
            float inv = 1.f / fmaxf((float)c, 1.f);
            size_t o = (size_t)node * 4 + seg;
            float4 z = ((const float4*)z1)[o];
            float4 bb = ((const float4*)b1)[seg];
            float hx = fmaxf(ax * inv + bb.x + z.x, 0.f);
            float hy = fmaxf(ay * inv + bb.y + z.y, 0.f);
            float hz = fmaxf(az * inv + bb.z + z.z, 0.f);
            float hw = fmaxf(aw * inv + bb.w + z.w, 0.f);
            float d0 = hx * U0.x + hy * U0.y + hz * U0.z + hw * U0.w;
            float d1 = hx * U1.x + hy * U1.y + hz * U1.z + hw * U1.w;
            float d2 = hx * U2.x + hy * U2.y + hz * U2.z + hw * U2.w;
            float d3 = hx * U3.x + hy * U3.y + hz * U3.z + hw * U3.w;
            d0 += __shfl_xor(d0, 1, 4); d0 += __shfl_xor(d0, 2, 4);
            d1 += __shfl_xor(d1, 1, 4); d1 += __shfl_xor(d1, 2, 4);
            d2 += __shfl_xor(d2, 1, 4); d2 += __shfl_xor(d2, 2, 4);
            d3 += __shfl_xor(d3, 1, 4); d3 += __shfl_xor(d3, 2, 4);
            float val = (seg == 0) ? d0 : (seg == 1) ? d1 : (seg == 2) ? d2 : d3;
            float* dp = (seg < 2) ? (qarr + (size_t)seg * N)
                                  : (parr + (size_t)(seg - 2) * N);
            dp[node] = val;
        }
    }
}

// ---------------------------------------------------------------------------
// K6: pair logits + BCE from collapsed scalars (R11 measured-best form).
// 2 lanes per pair (s = article slot). Per edge: ONE 4 B gather from the
// 400 KB q-plane (L2-resident).
// ---------------------------------------------------------------------------
__global__ __launch_bounds__(256) void k_pair(const float* __restrict__ qarr,
                                              const float* __restrict__ parr,
                                              const int* __restrict__ csr,
                                              const int* __restrict__ nodestart,
                                              const int* __restrict__ ncnt,
                                              const int* __restrict__ a1,
                                              const int* __restrict__ a2,
                                              const int* __restrict__ labels,
                                              const float* __restrict__ wsu,
                                              float* __restrict__ out_logits,
                                              float* __restrict__ lacc,
                                              int* __restrict__ ticket,
                                              float* __restrict__ out0,
                                              int B, float invB, int N) {
    __shared__ float lred[4];
    int t = blockIdx.x * 256 + threadIdx.x;
    int pid = t >> 1, s = t & 1;

    float hsum = 0.f;
    if (pid < B) {
        int node = s ? a2[pid] : a1[pid];
        int st = nodestart[node];
        int c = ncnt[node];
        const float* qs = qarr + (size_t)s * N;
        const int* ids = csr + st;
        float acc = 0.f;
        int k = 0;
        for (; k + 4 <= c; k += 4) {
            int n0 = ids[k], n1 = ids[k + 1], n2 = ids[k + 2], n3 = ids[k + 3];
            acc += (qs[n0] + qs[n1]) + (qs[n2] + qs[n3]);
        }
        for (; k < c; ++k) acc += qs[ids[k]];
        hsum = acc / fmaxf((float)c, 1.f) + parr[(size_t)s * N + node];
    }
    float other = __shfl_xor(hsum, 1, 2);
    float myloss = 0.f;
    if (pid < B && s == 0) {
        float l = hsum + other + wsu[64] + wsu[65];
        out_logits[pid] = l;
        float y = (float)labels[pid];
        myloss = fmaxf(l, 0.f) - l * y + log1pf(expf(-fabsf(l)));
    }
    // block loss reduction
    float v = myloss;
#pragma unroll
    for (int off = 32; off; off >>= 1) v += __shfl_down(v, off, 64);
    if ((threadIdx.x & 63) == 0) lred[threadIdx.x >> 6] = v;
    __syncthreads();
    if (threadIdx.x == 0) {
        float ssum = lred[0] + lred[1] + lred[2] + lred[3];
        atomicAdd(lacc, ssum);
        __threadfence();
        int tk = atomicAdd(ticket, 1);
        if (tk == (int)gridDim.x - 1) {
            __threadfence();
            float total = atomicAdd(lacc, 0.f);
            out0[0] = total * invB;
        }
    }
}

// ---------------------------------------------------------------------------
extern "C" void kernel_launch(void* const* d_in, const int* in_sizes, int n_in,
                              void* d_out, int out_size, void* d_ws, size_t ws_size,
                              hipStream_t stream) {
    const float* x    = (const float*)d_in[0];
    const float* w1l  = (const float*)d_in[1];
    const float* b1   = (const float*)d_in[2];
    const float* w1r  = (const float*)d_in[3];
    const float* w2l  = (const float*)d_in[4];
    const float* b2v  = (const float*)d_in[5];
    const float* w2r  = (const float*)d_in[6];
    const float* wc   = (const float*)d_in[7];
    const float* bc   = (const float*)d_in[8];
    const int*   ei   = (const int*)d_in[9];
    const int*   a1   = (const int*)d_in[10];
    const int*   a2   = (const int*)d_in[11];
    const int*   lab  = (const int*)d_in[12];

    const int N = in_sizes[0] / DD;
    const int E = in_sizes[9] / 2;
    const int B = in_sizes[10];
    const int NB = (N + BW - 1) / BW;       // 782 for N=100000 (needs N < 2^20)

    const int* src = ei;
    const int* dst = ei + E;

    const int E4 = E / 4;
    const int cblocks = (E4 + 1023) / 1024;          // 4096 edges per chunk

    // workspace layout
    char* ws = (char*)d_ws;
    float*    wsu    = (float*)ws;                            // 512 B
    unsigned* y1b    = (unsigned*)(ws + 512);                 // [N,16] bf16 (32 B/row)
    float*    z1     = (float*)   (ws + 512 + (size_t)N * 32);// [N,16] f32
    int*      packed = (int*)     (ws + 512 + (size_t)N * 96);// [cblocks*4096] sorted blocks
    const size_t PKSZ = (size_t)cblocks * 4096 * 4;
    int*      runofs = (int*)((char*)packed + PKSZ);          // [cblocks*1024] offsets
    const size_t RSZ  = (size_t)cblocks * 1024 * 4;
    int*      csr    = (int*)((char*)runofs + RSZ);           // [NB*4096] gapped
    const size_t CSZ  = (size_t)NB * 4096 * 4;
    char*     p4     = (char*)csr + CSZ;
    int*   nodest  = (int*)p4;                               // [N]
    int*   ncnt    = (int*)(p4 + (size_t)N * 4);             // [N]
    float* qarr    = (float*)(p4 + (size_t)N * 8);           // [2N] planes q0,q1
    float* parr    = (float*)(p4 + (size_t)N * 16);          // [2N] planes p0,p1
    float* lacc    = (float*)(p4 + (size_t)N * 24);          // zeroed by k_front prep
    int*   ticket  = (int*)((char*)lacc + 4);                // zeroed by k_front prep

    float* out = (float*)d_out;       // out[0] = loss, out[1..B] = logits

    k_front<<<cblocks + 1 + XG, 256, 0, stream>>>(src, dst, packed, runofs,
                                                  E4, NB, cblocks,
                                                  w2l, w2r, b2v, wc, bc, wsu,
                                                  x, w1l, w1r, y1b, z1, N,
                                                  lacc, ticket);

    k_sortagg<<<NB, 256, 0, stream>>>(packed, runofs, cblocks,
                                      nodest, ncnt, csr,
                                      y1b, z1, b1, wsu, qarr, parr, N);

    k_pair<<<(B * 2 + 255) / 256, 256, 0, stream>>>(qarr, parr, csr, nodest, ncnt,
                                                    a1, a2, lab, wsu,
                                                    out + 1, lacc, ticket, out,
                                                    B, 1.0f / (float)B, N);
}